// Round 7
// baseline (1049.756 us; speedup 1.0000x reference)
//
#include <hip/hip_runtime.h>
#include <hip/hip_bf16.h>

// BNN MC-prediction: S=100 weight samples, batch 64, dims 784->512->512->10.
// R10 == R9 byte-identical resubmit ("container failed twice" with no
// compile/test output; R7 — same structure, same register pressure — ran
// fine, so this is an infra flake, not a kernel defect).
//
// Design (R7/R8/R9): barrier-free 4-samples-per-wave GEMM. Evidence: R3->R4
// (2x waves, same bytes) no change; R4->R6 (0.5x bytes via shared staging +
// per-tile block barriers) only ~5% -> TLP never materializes and block
// barriers serialize straggler latency. Keep R3's proven barrier-free
// single-wave pipeline; get the byte cut in-register: each wave owns 4
// samples; the psm (sigma/mean) k-tile is loaded ONCE and reused for all 4
// samples' transforms; eps for all 4 samples is ping-pong prefetched one
// FULL tile (~1100cy of work) ahead, exceeding HBM latency. A: shared (L0)
// or per-sample L2-hot loads at tile start (L1).
// R8 fix retained: aP includes sb*aStride. R9 fix retained: layer-1 launch
// passes 11 args (ASHARED is a template param).

typedef __bf16 bf16x8 __attribute__((ext_vector_type(8)));
typedef float f32x4 __attribute__((ext_vector_type(4)));

#define NSAMP 100
#define BATCH 64
#define D0 784
#define D1 512
#define D2 512
#define DOUT 10
#define K0PAD 800   // 784 padded to multiple of 32 (A side zero-padded)
#define RSB 40      // smB row stride in shorts (80 B rows)

__device__ __forceinline__ unsigned short f2bf(float f) {
    __bf16 b = (__bf16)f;
    return __builtin_bit_cast(unsigned short, b);
}
// packed dword: high16 = bf16(sigma), low16 = bf16(mean)
__device__ __forceinline__ float bf_hi(unsigned int u) {
    return __builtin_bit_cast(float, u & 0xffff0000u);
}
__device__ __forceinline__ float bf_lo(unsigned int u) {
    return __builtin_bit_cast(float, u << 16);
}

union FragU { uint4 q; bf16x8 v; };

// ---------------- precompute ----------------
#define XB_N   (BATCH * K0PAD)
#define PS0_N  (D0 * D1)
#define PS1_N  (D1 * D2)
#define SGL_N  (D2 * DOUT)
#define B0_N   (NSAMP * D1)
#define B1_N   (NSAMP * D2)
#define BL_N   (NSAMP * DOUT)
#define PREP_TOTAL (XB_N + PS0_N + PS1_N + SGL_N + B0_N + B1_N + BL_N)

__global__ __launch_bounds__(256) void prep(
    const float* __restrict__ inputs,
    const float* __restrict__ wv0, const float* __restrict__ wm0,
    const float* __restrict__ wv1, const float* __restrict__ wm1,
    const float* __restrict__ wvl,
    const float* __restrict__ be0, const float* __restrict__ bv0, const float* __restrict__ bm0,
    const float* __restrict__ be1, const float* __restrict__ bv1, const float* __restrict__ bm1,
    const float* __restrict__ bel, const float* __restrict__ bvl, const float* __restrict__ bml,
    unsigned short* __restrict__ Xb,
    unsigned int* __restrict__ psm0, unsigned int* __restrict__ psm1,
    float* __restrict__ sigmal,
    float* __restrict__ bias0, float* __restrict__ bias1, float* __restrict__ biasl)
{
    int i = blockIdx.x * 256 + threadIdx.x;
    if (i < XB_N) {
        int m = i / K0PAD, k = i % K0PAD;
        float v = (k < D0) ? inputs[m * D0 + k] : 0.f;
        Xb[i] = f2bf(v);
        return;
    }
    i -= XB_N;
    if (i < PS0_N) {
        unsigned int sg = f2bf(__expf(0.5f * wv0[i]));
        unsigned int mn = f2bf(wm0[i]);
        psm0[i] = (sg << 16) | mn;
        return;
    }
    i -= PS0_N;
    if (i < PS1_N) {
        unsigned int sg = f2bf(__expf(0.5f * wv1[i]));
        unsigned int mn = f2bf(wm1[i]);
        psm1[i] = (sg << 16) | mn;
        return;
    }
    i -= PS1_N;
    if (i < SGL_N) { sigmal[i] = __expf(0.5f * wvl[i]); return; }
    i -= SGL_N;
    if (i < B0_N) { int n = i % D1; bias0[i] = fmaf(be0[i], __expf(0.5f * bv0[n]), bm0[n]); return; }
    i -= B0_N;
    if (i < B1_N) { int n = i % D2; bias1[i] = fmaf(be1[i], __expf(0.5f * bv1[n]), bm1[n]); return; }
    i -= B1_N;
    if (i < BL_N) { int o = i % DOUT; biasl[i] = fmaf(bel[i], __expf(0.5f * bvl[o]), bml[o]); return; }
}

// ------ barrier-free 4-sample/wave fused-sampling GEMM, one wave per block ------
// Block = 1 wave, owns samples sb..sb+3, output 64(M) x 32(N) per sample.
// psm tile loaded once per k-tile, reused across the 4 samples in-register.
// eps (HBM stream) ping-pong prefetched one full tile ahead. No barriers:
// smB is wave-private; DS ops are in-order within a wave.
template<int ASHARED>
__global__ __launch_bounds__(64) void gemm_s4(
    const unsigned short* __restrict__ A, int lda, long aStride,   // bf16 [.][64][lda]
    const float* __restrict__ eps, long eStride,                   // fp32 [S][Kvalid][512]
    const unsigned int* __restrict__ psm,                          // packed [Kvalid][512]
    int KT, int Kvalid,                                            // K = KT*32 (A padded)
    const float* __restrict__ bias,                                // [S][512]
    void* __restrict__ outp, int outBf16)                          // [S][64][512]
{
    __shared__ unsigned short smB[2][32 * RSB];   // 2x2560 B, wave-private ping-pong

    const int bx = blockIdx.x;
    const int sb = (bx >> 4) << 2;     // sample base (25 groups of 4)
    const int n0 = (bx & 15) << 5;     // 16 n-tiles of 32
    const int l  = threadIdx.x;        // 0..63
    const int fr = l & 15, quad = l >> 4;
    const int kg = l >> 3;             // 0..7 : k-subgroup (4 rows each)
    const int ng = l & 7;              // 0..7 : n-group of 4 floats

    // R8 fix: include the sample-group base here (aStride=0 for ASHARED)
    const unsigned short* aP = A + (long)sb * aStride + (long)fr * lda + quad * 8;
    const float* eB        = eps + (long)sb * eStride + n0 + 4 * ng;
    const unsigned int* pB = psm + n0 + 4 * ng;

    f32x4 acc[4][4][2] = {};           // [sample][mi][ni] : 128 VGPR
    float4 eaA[4][4], eaB[4][4];       // [sample][j] eps frags, tile ping-pong
    uint4  paA[4], paB[4];             // psm frags, tile ping-pong
    uint4  aaS[4];                     // ASHARED: A frags (shared across samples)
    uint4  aaP[4][4];                  // !ASHARED: [sample][mi] A frags

    // prefetch group for tile kt: psm tile + eps tile for all 4 samples
    auto issueEpsPA = [&](int kt, float4 (*ea)[4], uint4* pa) {
        const int kb = kt * 32;
#pragma unroll
        for (int j = 0; j < 4; ++j) {
            const int row = kb + 4 * kg + j;
            const bool ok = row < Kvalid;
            const long off = (long)(ok ? row : 0) * 512;   // clamp: never OOB
            uint4 p = *reinterpret_cast<const uint4*>(pB + off);
            if (!ok) p = uint4{0u, 0u, 0u, 0u};
            pa[j] = p;
#pragma unroll
            for (int si = 0; si < 4; ++si) {
                float4 e = *reinterpret_cast<const float4*>(eB + (long)si * eStride + off);
                if (!ok) e = float4{0.f, 0.f, 0.f, 0.f};
                ea[si][j] = e;
            }
        }
    };

    // current-tile A loads (L0: 4 shared frags; L1: 16 per-sample, L2-hot)
    auto issueAA = [&](int kt) {
        const int kb = kt * 32;
        if constexpr (ASHARED) {
#pragma unroll
            for (int mi = 0; mi < 4; ++mi)
                aaS[mi] = *reinterpret_cast<const uint4*>(aP + (long)(mi * 16) * lda + kb);
        } else {
#pragma unroll
            for (int si = 0; si < 4; ++si)
#pragma unroll
                for (int mi = 0; mi < 4; ++mi)
                    aaP[si][mi] = *reinterpret_cast<const uint4*>(
                        aP + (long)si * aStride + (long)(mi * 16) * lda + kb);
        }
    };

    // transform one sample's W frags + in-register transpose -> smB[buf]
    auto stage = [&](const float4* ea, const uint4* pa, int buf) {
        float wv[4][4];   // wv[j][i] = W[k=4kg+j][n=4ng+i]
#pragma unroll
        for (int j = 0; j < 4; ++j) {
            wv[j][0] = fmaf(ea[j].x, bf_hi(pa[j].x), bf_lo(pa[j].x));
            wv[j][1] = fmaf(ea[j].y, bf_hi(pa[j].y), bf_lo(pa[j].y));
            wv[j][2] = fmaf(ea[j].z, bf_hi(pa[j].z), bf_lo(pa[j].z));
            wv[j][3] = fmaf(ea[j].w, bf_hi(pa[j].w), bf_lo(pa[j].w));
        }
#pragma unroll
        for (int i = 0; i < 4; ++i) {
            uint2 d;
            d.x = (unsigned)f2bf(wv[0][i]) | ((unsigned)f2bf(wv[1][i]) << 16);
            d.y = (unsigned)f2bf(wv[2][i]) | ((unsigned)f2bf(wv[3][i]) << 16);
            *reinterpret_cast<uint2*>(&smB[buf][(4 * ng + i) * RSB + 4 * kg]) = d;  // 8B-aligned
        }
    };

    auto compute = [&](int si, int buf) {
        FragU bf0, bf1;   // B[k=quad*8+j][n=fr] : contiguous 16 B in [n][k] rows
        bf0.q = *reinterpret_cast<const uint4*>(&smB[buf][fr * RSB + quad * 8]);
        bf1.q = *reinterpret_cast<const uint4*>(&smB[buf][(16 + fr) * RSB + quad * 8]);
#pragma unroll
        for (int mi = 0; mi < 4; ++mi) {
            FragU af;
            if constexpr (ASHARED) af.q = aaS[mi];
            else                   af.q = aaP[si][mi];
            acc[si][mi][0] = __builtin_amdgcn_mfma_f32_16x16x32_bf16(af.v, bf0.v, acc[si][mi][0], 0, 0, 0);
            acc[si][mi][1] = __builtin_amdgcn_mfma_f32_16x16x32_bf16(af.v, bf1.v, acc[si][mi][1], 0, 0, 0);
        }
    };

    // 4 samples through the wave-private smB ping-pong; in-order DS => no barrier
    auto tileBody = [&](const float4 (*ea)[4], const uint4* pa) {
#pragma unroll
        for (int si = 0; si < 4; ++si) {
            stage(ea[si], pa, si & 1);
            compute(si, si & 1);
        }
    };

    // prologue + main loop (tile-level ping-pong, duplicated bodies: no
    // runtime-indexed register arrays)
    issueEpsPA(0, eaA, paA);
    int kt = 0;
    while (kt < KT) {
        {   // even tile: consume A-set, prefetch into B-set
            if (kt + 1 < KT) issueEpsPA(kt + 1, eaB, paB);
            issueAA(kt);
            tileBody(eaA, paA);
        }
        ++kt;
        if (kt >= KT) break;
        {   // odd tile: consume B-set, prefetch into A-set
            if (kt + 1 < KT) issueEpsPA(kt + 1, eaA, paA);
            issueAA(kt);
            tileBody(eaB, paB);
        }
        ++kt;
    }

    // epilogue: bias + relu + store, per sample
#pragma unroll
    for (int si = 0; si < 4; ++si) {
        const int s = sb + si;
        const float bv0v = bias[(long)s * 512 + n0 + fr];
        const float bv1v = bias[(long)s * 512 + n0 + 16 + fr];
        const long outBase = (long)s * BATCH * 512;
#pragma unroll
        for (int mi = 0; mi < 4; ++mi) {
#pragma unroll
            for (int ni = 0; ni < 2; ++ni) {
                const float bv = ni ? bv1v : bv0v;
                const int col = n0 + ni * 16 + fr;
#pragma unroll
                for (int r = 0; r < 4; ++r) {
                    const int row = mi * 16 + quad * 4 + r;
                    float v = fmaxf(acc[si][mi][ni][r] + bv, 0.f);
                    const long idx = outBase + (long)row * 512 + col;
                    if (outBf16) ((unsigned short*)outp)[idx] = f2bf(v);
                    else         ((float*)outp)[idx] = v;
                }
            }
        }
    }
}

// ---------------- final layer: [64,512] @ [512,10] + bias, fp32 VALU ----------------
__global__ __launch_bounds__(320) void last_layer(
    const float* __restrict__ act2,   // [S][64][512]
    const float* __restrict__ wel,    // [S][512][10]
    const float* __restrict__ sigmal, // [512][10]
    const float* __restrict__ wml,    // [512][10]
    const float* __restrict__ biasl,  // [S][10]
    float* __restrict__ out)          // [S][64][10]
{
    __shared__ float smW[D2 * DOUT];  // 20 KB
    const int s = blockIdx.x;
    const int t = threadIdx.x;
    const float* we = wel + (long)s * D2 * DOUT;
    for (int i = t; i < D2 * DOUT; i += 320)
        smW[i] = fmaf(we[i], sigmal[i], wml[i]);
    __syncthreads();

    const int m  = t / 5;
    const int op = t % 5;
    const float* a = act2 + ((long)s * BATCH + m) * D2;
    float acc0 = 0.f, acc1 = 0.f;
#pragma unroll 4
    for (int k = 0; k < D2; k += 4) {
        float4 av = *reinterpret_cast<const float4*>(a + k);
        acc0 = fmaf(av.x, smW[(k + 0) * DOUT + op], acc0);
        acc0 = fmaf(av.y, smW[(k + 1) * DOUT + op], acc0);
        acc0 = fmaf(av.z, smW[(k + 2) * DOUT + op], acc0);
        acc0 = fmaf(av.w, smW[(k + 3) * DOUT + op], acc0);
        acc1 = fmaf(av.x, smW[(k + 0) * DOUT + op + 5], acc1);
        acc1 = fmaf(av.y, smW[(k + 1) * DOUT + op + 5], acc1);
        acc1 = fmaf(av.z, smW[(k + 2) * DOUT + op + 5], acc1);
        acc1 = fmaf(av.w, smW[(k + 3) * DOUT + op + 5], acc1);
    }
    const long ob = ((long)s * BATCH + m) * DOUT;
    out[ob + op]     = acc0 + biasl[s * DOUT + op];
    out[ob + op + 5] = acc1 + biasl[s * DOUT + op + 5];
}

extern "C" void kernel_launch(void* const* d_in, const int* in_sizes, int n_in,
                              void* d_out, int out_size, void* d_ws, size_t ws_size,
                              hipStream_t stream)
{
    const float* inputs = (const float*)d_in[0];
    // d_in[1] = task_id (unused)
    const float* wm0 = (const float*)d_in[2];
    const float* wv0 = (const float*)d_in[3];
    const float* bm0 = (const float*)d_in[4];
    const float* bv0 = (const float*)d_in[5];
    const float* wm1 = (const float*)d_in[6];
    const float* wv1 = (const float*)d_in[7];
    const float* bm1 = (const float*)d_in[8];
    const float* bv1 = (const float*)d_in[9];
    const float* wml = (const float*)d_in[10];
    const float* wvl = (const float*)d_in[11];
    const float* bml = (const float*)d_in[12];
    const float* bvl = (const float*)d_in[13];
    const float* we0 = (const float*)d_in[14];
    const float* be0 = (const float*)d_in[15];
    const float* we1 = (const float*)d_in[16];
    const float* be1 = (const float*)d_in[17];
    const float* wel = (const float*)d_in[18];
    const float* bel = (const float*)d_in[19];

    // workspace carve (~23 MB, all chunks 16B-aligned)
    char* w = (char*)d_ws;
    unsigned short* Xb  = (unsigned short*)w; w += (size_t)XB_N * 2;
    unsigned int* psm0  = (unsigned int*)w;   w += (size_t)PS0_N * 4;
    unsigned int* psm1  = (unsigned int*)w;   w += (size_t)PS1_N * 4;
    float* sigmal = (float*)w; w += (size_t)SGL_N * 4;
    float* bias0  = (float*)w; w += (size_t)B0_N * 4;
    float* bias1  = (float*)w; w += (size_t)B1_N * 4;
    float* biasl  = (float*)w; w += (size_t)BL_N * 4;
    unsigned short* act1 = (unsigned short*)w; w += (size_t)NSAMP * BATCH * D1 * 2;
    float* act2 = (float*)w; w += (size_t)NSAMP * BATCH * D2 * 4;

    prep<<<dim3((PREP_TOTAL + 255) / 256), 256, 0, stream>>>(
        inputs, wv0, wm0, wv1, wm1, wvl,
        be0, bv0, bm0, be1, bv1, bm1, bel, bvl, bml,
        Xb, psm0, psm1, sigmal, bias0, bias1, biasl);

    // layer 0: A = Xb shared across samples (aStride=0), K=800 pad, Kvalid=784
    gemm_s4<1><<<dim3((NSAMP / 4) * 16), 64, 0, stream>>>(
        Xb, K0PAD, 0L, we0, (long)D0 * D1, psm0,
        K0PAD / 32, D0, bias0, (void*)act1, 1);

    // layer 1: per-sample A, K = 512 exact
    gemm_s4<0><<<dim3((NSAMP / 4) * 16), 64, 0, stream>>>(
        act1, D1, (long)BATCH * D1, we1, (long)D1 * D2, psm1,
        D1 / 32, D1, bias1, (void*)act2, 0);

    last_layer<<<dim3(NSAMP), 320, 0, stream>>>(
        act2, wel, sigmal, wml, biasl, (float*)d_out);
}

// Round 9
// 449.590 us; speedup vs baseline: 2.3349x; 2.3349x over previous
//
#include <hip/hip_runtime.h>
#include <hip/hip_bf16.h>

// BNN MC-prediction: S=100 weight samples, batch 64, dims 784->512->512->10.
// R12 == R11 byte-identical resubmit (third "container failed twice"; the
// prior two such failures both passed on resubmit -> infra flake. Audit
// found no kernel-side fault: 157MB < ~640MB ws, all indices in bounds, no
// barriers, ~70 VGPR).
//
// R11: precompute-W split. R10's spill disaster (256 VGPR, 423MB scratch
// writes) killed 4-samples-in-register; deeper evidence: the fused
// eps->transform->LDS-transpose->MFMA pipeline runs at ~1 VMEM inst/123
// CU-cycles regardless of waves (R4) or bytes (R6), while trivial streaming
// kernels (harness fills) hit 6.9 TB/s on this machine. So: move the
// transform into a streaming-class kernel. build_w materializes
// W = eps*sigma+mean as bf16 in EXACT MFMA B-fragment layout
// ([S][32 nb][KT][64 lanes] x 16B frag tiles; gather-read eps in full-line
// 4x64B segments, coalesced 1KB writes). gemm_pw then needs NO LDS, NO
// transform, NO clamps: 5 loads + 8 MFMA per k-tile, 1 wave per
// (sample, 16-col block) = 3200 waves (3.1/SIMD), ~50 VGPR.

typedef __bf16 bf16x8 __attribute__((ext_vector_type(8)));
typedef float f32x4 __attribute__((ext_vector_type(4)));

#define NSAMP 100
#define BATCH 64
#define D0 784
#define D1 512
#define D2 512
#define DOUT 10
#define K0PAD 800   // 784 padded to multiple of 32 (A side zero-padded)
#define KT0 (K0PAD / 32)   // 25
#define KT1 (D1 / 32)      // 16

__device__ __forceinline__ unsigned short f2bf(float f) {
    __bf16 b = (__bf16)f;
    return __builtin_bit_cast(unsigned short, b);
}
// packed dword: high16 = bf16(sigma), low16 = bf16(mean)
__device__ __forceinline__ float bf_hi(unsigned int u) {
    return __builtin_bit_cast(float, u & 0xffff0000u);
}
__device__ __forceinline__ float bf_lo(unsigned int u) {
    return __builtin_bit_cast(float, u << 16);
}

union FragU { uint4 q; bf16x8 v; };

// ---------------- precompute 1: inputs, psm packs, biases ----------------
#define XB_N   (BATCH * K0PAD)
#define PS0_N  (D0 * D1)
#define PS1_N  (D1 * D2)
#define SGL_N  (D2 * DOUT)
#define B0_N   (NSAMP * D1)
#define B1_N   (NSAMP * D2)
#define BL_N   (NSAMP * DOUT)
#define PREP_TOTAL (XB_N + PS0_N + PS1_N + SGL_N + B0_N + B1_N + BL_N)

__global__ __launch_bounds__(256) void prep(
    const float* __restrict__ inputs,
    const float* __restrict__ wv0, const float* __restrict__ wm0,
    const float* __restrict__ wv1, const float* __restrict__ wm1,
    const float* __restrict__ wvl,
    const float* __restrict__ be0, const float* __restrict__ bv0, const float* __restrict__ bm0,
    const float* __restrict__ be1, const float* __restrict__ bv1, const float* __restrict__ bm1,
    const float* __restrict__ bel, const float* __restrict__ bvl, const float* __restrict__ bml,
    unsigned short* __restrict__ Xb,
    unsigned int* __restrict__ psm0, unsigned int* __restrict__ psm1,
    float* __restrict__ sigmal,
    float* __restrict__ bias0, float* __restrict__ bias1, float* __restrict__ biasl)
{
    int i = blockIdx.x * 256 + threadIdx.x;
    if (i < XB_N) {
        int m = i / K0PAD, k = i % K0PAD;
        float v = (k < D0) ? inputs[m * D0 + k] : 0.f;
        Xb[i] = f2bf(v);
        return;
    }
    i -= XB_N;
    if (i < PS0_N) {
        unsigned int sg = f2bf(__expf(0.5f * wv0[i]));
        unsigned int mn = f2bf(wm0[i]);
        psm0[i] = (sg << 16) | mn;
        return;
    }
    i -= PS0_N;
    if (i < PS1_N) {
        unsigned int sg = f2bf(__expf(0.5f * wv1[i]));
        unsigned int mn = f2bf(wm1[i]);
        psm1[i] = (sg << 16) | mn;
        return;
    }
    i -= PS1_N;
    if (i < SGL_N) { sigmal[i] = __expf(0.5f * wvl[i]); return; }
    i -= SGL_N;
    if (i < B0_N) { int n = i % D1; bias0[i] = fmaf(be0[i], __expf(0.5f * bv0[n]), bm0[n]); return; }
    i -= B0_N;
    if (i < B1_N) { int n = i % D2; bias1[i] = fmaf(be1[i], __expf(0.5f * bv1[n]), bm1[n]); return; }
    i -= B1_N;
    if (i < BL_N) { int o = i % DOUT; biasl[i] = fmaf(bel[i], __expf(0.5f * bvl[o]), bml[o]); return; }
}

// ---------------- precompute 2: W in MFMA B-fragment layout ----------------
// One wave builds the 1KB frag-tile for 4 samples at (nb, kt): lane l holds
// 8 bf16 along k: W[kt*32 + (l>>4)*8 + t][nb*16 + (l&15)], t=0..7.
// eps gather: per j-load a wave touches 4 full 64B lines (16 consecutive n
// x 4 k-rows) -> no overfetch. psm (2.6MB) reused 100x across s -> L2-hot.
// Write: 64 lanes x 16B = 1KB contiguous, perfectly coalesced.
__global__ __launch_bounds__(64) void build_w(
    const float* __restrict__ eps, long eStride,   // [S][Kvalid][512] fp32
    const unsigned int* __restrict__ psm,          // [Kvalid][512] packed
    uint4* __restrict__ Wb,                        // [S][32][KT][64] frag tiles
    int KT, int Kvalid)
{
    const int bid = blockIdx.x;
    const int kt  = bid % KT;
    const int nb  = (bid / KT) & 31;
    const int sg  = bid / (KT * 32);               // 25 groups of 4 samples
    const int l   = threadIdx.x;
    const int fr  = l & 15, quad = l >> 4;
    const int col   = nb * 16 + fr;
    const int kbase = kt * 32 + quad * 8;

    int rows[8];
    unsigned int pv[8];
#pragma unroll
    for (int j = 0; j < 8; ++j) {
        int r = kbase + j; if (r >= Kvalid) r = Kvalid - 1;   // pad rows: finite garbage, A=0 there
        rows[j] = r;
        pv[j] = psm[(long)r * 512 + col];
    }
#pragma unroll
    for (int si = 0; si < 4; ++si) {
        const int s = sg * 4 + si;
        const float* eB = eps + (long)s * eStride + col;
        float w[8];
#pragma unroll
        for (int j = 0; j < 8; ++j) {
            float e = eB[(long)rows[j] * 512];
            w[j] = fmaf(e, bf_hi(pv[j]), bf_lo(pv[j]));
        }
        uint4 o;
        o.x = (unsigned)f2bf(w[0]) | ((unsigned)f2bf(w[1]) << 16);
        o.y = (unsigned)f2bf(w[2]) | ((unsigned)f2bf(w[3]) << 16);
        o.z = (unsigned)f2bf(w[4]) | ((unsigned)f2bf(w[5]) << 16);
        o.w = (unsigned)f2bf(w[6]) | ((unsigned)f2bf(w[7]) << 16);
        Wb[(((long)s * 32 + nb) * KT + kt) * 64 + l] = o;
    }
}

// ---------------- frag-direct GEMM: no LDS, no transform, no clamps ----------
// One wave per (sample, 16-col block): grid S*32. Per k-tile: 4 A-frag loads
// (L2-hot) + 1 W-frag load (read-once, coalesced 1KB) + 4 MFMA. Ping-pong
// register prefetch one tile ahead. aStride=0 makes A shared (layer 0).
__global__ __launch_bounds__(64) void gemm_pw(
    const unsigned short* __restrict__ A, int lda, long aStride,  // bf16 [.][64][lda]
    const uint4* __restrict__ Wb,                                 // [S][32][KT][64]
    int KT,
    const float* __restrict__ bias,                               // [S][512]
    void* __restrict__ outp, int outBf16)                         // [S][64][512]
{
    const int bx = blockIdx.x;
    const int s  = bx >> 5;            // 32 nb16 blocks per sample
    const int nb = bx & 31;
    const int l  = threadIdx.x;
    const int fr = l & 15, quad = l >> 4;

    const unsigned short* aP = A + (long)s * aStride + (long)fr * lda + quad * 8;
    const uint4* wP = Wb + ((long)s * 32 + nb) * KT * 64 + l;

    f32x4 acc[4] = {};                 // acc[mi], 16 regs (AGPR)
    uint4 wA, wB, aA[4], aB[4];

    auto issue = [&](int kt, uint4& w, uint4* a) {
        w = wP[(long)kt * 64];
        const int kb = kt * 32;
#pragma unroll
        for (int mi = 0; mi < 4; ++mi)
            a[mi] = *reinterpret_cast<const uint4*>(aP + (long)(mi * 16) * lda + kb);
    };
    auto comp = [&](const uint4& w, const uint4* a) {
        FragU bf; bf.q = w;
#pragma unroll
        for (int mi = 0; mi < 4; ++mi) {
            FragU af; af.q = a[mi];
            acc[mi] = __builtin_amdgcn_mfma_f32_16x16x32_bf16(af.v, bf.v, acc[mi], 0, 0, 0);
        }
    };

    issue(0, wA, aA);
    int kt = 0;
    while (kt < KT) {
        if (kt + 1 < KT) issue(kt + 1, wB, aB);
        comp(wA, aA);
        ++kt;
        if (kt >= KT) break;
        if (kt + 1 < KT) issue(kt + 1, wA, aA);
        comp(wB, aB);
        ++kt;
    }

    // epilogue: bias + relu + store (col = nb*16+fr fixed per lane)
    const float bv = bias[(long)s * 512 + nb * 16 + fr];
    const long outBase = (long)s * BATCH * 512 + nb * 16 + fr;
#pragma unroll
    for (int mi = 0; mi < 4; ++mi) {
#pragma unroll
        for (int r = 0; r < 4; ++r) {
            const int row = mi * 16 + quad * 4 + r;
            float v = fmaxf(acc[mi][r] + bv, 0.f);
            const long idx = outBase + (long)row * 512;
            if (outBf16) ((unsigned short*)outp)[idx] = f2bf(v);
            else         ((float*)outp)[idx] = v;
        }
    }
}

// ---------------- final layer: [64,512] @ [512,10] + bias, fp32 VALU ----------------
__global__ __launch_bounds__(320) void last_layer(
    const float* __restrict__ act2,   // [S][64][512]
    const float* __restrict__ wel,    // [S][512][10]
    const float* __restrict__ sigmal, // [512][10]
    const float* __restrict__ wml,    // [512][10]
    const float* __restrict__ biasl,  // [S][10]
    float* __restrict__ out)          // [S][64][10]
{
    __shared__ float smW[D2 * DOUT];  // 20 KB
    const int s = blockIdx.x;
    const int t = threadIdx.x;
    const float* we = wel + (long)s * D2 * DOUT;
    for (int i = t; i < D2 * DOUT; i += 320)
        smW[i] = fmaf(we[i], sigmal[i], wml[i]);
    __syncthreads();

    const int m  = t / 5;
    const int op = t % 5;
    const float* a = act2 + ((long)s * BATCH + m) * D2;
    float acc0 = 0.f, acc1 = 0.f;
#pragma unroll 4
    for (int k = 0; k < D2; k += 4) {
        float4 av = *reinterpret_cast<const float4*>(a + k);
        acc0 = fmaf(av.x, smW[(k + 0) * DOUT + op], acc0);
        acc0 = fmaf(av.y, smW[(k + 1) * DOUT + op], acc0);
        acc0 = fmaf(av.z, smW[(k + 2) * DOUT + op], acc0);
        acc0 = fmaf(av.w, smW[(k + 3) * DOUT + op], acc0);
        acc1 = fmaf(av.x, smW[(k + 0) * DOUT + op + 5], acc1);
        acc1 = fmaf(av.y, smW[(k + 1) * DOUT + op + 5], acc1);
        acc1 = fmaf(av.z, smW[(k + 2) * DOUT + op + 5], acc1);
        acc1 = fmaf(av.w, smW[(k + 3) * DOUT + op + 5], acc1);
    }
    const long ob = ((long)s * BATCH + m) * DOUT;
    out[ob + op]     = acc0 + biasl[s * DOUT + op];
    out[ob + op + 5] = acc1 + biasl[s * DOUT + op + 5];
}

extern "C" void kernel_launch(void* const* d_in, const int* in_sizes, int n_in,
                              void* d_out, int out_size, void* d_ws, size_t ws_size,
                              hipStream_t stream)
{
    const float* inputs = (const float*)d_in[0];
    // d_in[1] = task_id (unused)
    const float* wm0 = (const float*)d_in[2];
    const float* wv0 = (const float*)d_in[3];
    const float* bm0 = (const float*)d_in[4];
    const float* bv0 = (const float*)d_in[5];
    const float* wm1 = (const float*)d_in[6];
    const float* wv1 = (const float*)d_in[7];
    const float* bm1 = (const float*)d_in[8];
    const float* bv1 = (const float*)d_in[9];
    const float* wml = (const float*)d_in[10];
    const float* wvl = (const float*)d_in[11];
    const float* bml = (const float*)d_in[12];
    const float* bvl = (const float*)d_in[13];
    const float* we0 = (const float*)d_in[14];
    const float* be0 = (const float*)d_in[15];
    const float* we1 = (const float*)d_in[16];
    const float* be1 = (const float*)d_in[17];
    const float* wel = (const float*)d_in[18];
    const float* bel = (const float*)d_in[19];

    // workspace carve (~157 MB, all chunks 16B-aligned)
    char* w = (char*)d_ws;
    unsigned short* Xb  = (unsigned short*)w; w += (size_t)XB_N * 2;
    unsigned int* psm0  = (unsigned int*)w;   w += (size_t)PS0_N * 4;
    unsigned int* psm1  = (unsigned int*)w;   w += (size_t)PS1_N * 4;
    float* sigmal = (float*)w; w += (size_t)SGL_N * 4;
    float* bias0  = (float*)w; w += (size_t)B0_N * 4;
    float* bias1  = (float*)w; w += (size_t)B1_N * 4;
    float* biasl  = (float*)w; w += (size_t)BL_N * 4;
    unsigned short* act1 = (unsigned short*)w; w += (size_t)NSAMP * BATCH * D1 * 2;
    float* act2 = (float*)w; w += (size_t)NSAMP * BATCH * D2 * 4;
    uint4* W0 = (uint4*)w; w += (size_t)NSAMP * 32 * KT0 * 64 * 16;   // 81.9 MB
    uint4* W1 = (uint4*)w; w += (size_t)NSAMP * 32 * KT1 * 64 * 16;   // 52.4 MB

    prep<<<dim3((PREP_TOTAL + 255) / 256), 256, 0, stream>>>(
        inputs, wv0, wm0, wv1, wm1, wvl,
        be0, bv0, bm0, be1, bv1, bm1, bel, bvl, bml,
        Xb, psm0, psm1, sigmal, bias0, bias1, biasl);

    // W materialization (streaming class): one wave per (4-sample group, nb, kt)
    build_w<<<dim3((NSAMP / 4) * 32 * KT0), 64, 0, stream>>>(
        we0, (long)D0 * D1, psm0, W0, KT0, D0);
    build_w<<<dim3((NSAMP / 4) * 32 * KT1), 64, 0, stream>>>(
        we1, (long)D1 * D2, psm1, W1, KT1, D1);

    // layer 0: A = Xb shared across samples (aStride=0), K=800 pad
    gemm_pw<<<dim3(NSAMP * 32), 64, 0, stream>>>(
        Xb, K0PAD, 0L, W0, KT0, bias0, (void*)act1, 1);

    // layer 1: per-sample A
    gemm_pw<<<dim3(NSAMP * 32), 64, 0, stream>>>(
        act1, D1, (long)BATCH * D1, W1, KT1, bias1, (void*)act2, 0);

    last_layer<<<dim3(NSAMP), 320, 0, stream>>>(
        act2, wel, sigmal, wml, biasl, (float*)d_out);
}